// Round 1
// baseline (158.623 us; speedup 1.0000x reference)
//
#include <hip/hip_runtime.h>
#include <stdint.h>
#include <math.h>

#define B_ 16
#define T_ 512
#define C_ 3
#define V_ 16
#define H_ 128
#define NC_ 12

// workspace layout (float offsets)
#define WS_W2T   0        // 16384: w2 transposed [o][p]
#define WS_INV1  16384    // 128
#define WS_D1    16512    // 128
#define WS_INV2  16640    // 128
#define WS_D2    16768    // 128
#define WS_FEAT  16896    // 2048: per-(b,h) spike totals
// total 18944 floats = 75776 bytes

__global__ void prep_kernel(const float* __restrict__ w2,
                            const float* __restrict__ g1, const float* __restrict__ be1,
                            const float* __restrict__ m1, const float* __restrict__ rv1,
                            const float* __restrict__ g2, const float* __restrict__ be2,
                            const float* __restrict__ m2, const float* __restrict__ rv2,
                            float* __restrict__ ws) {
    int i = blockIdx.x * blockDim.x + threadIdx.x;
    if (i < H_ * H_) {
        int o = i >> 7, p = i & (H_ - 1);
        ws[WS_W2T + i] = w2[p * H_ + o];   // w2t[o][p] = w2[p][o]
    }
    if (i < H_) {
        float r1 = (float)(1.0 / sqrt((double)(rv1[i] + 1e-5f)));
        float inv1 = g1[i] * r1;
        ws[WS_INV1 + i] = inv1;
        ws[WS_D1 + i] = be1[i] - m1[i] * inv1;
        float r2 = (float)(1.0 / sqrt((double)(rv2[i] + 1e-5f)));
        float inv2 = g2[i] * r2;
        ws[WS_INV2 + i] = inv2;
        ws[WS_D2 + i] = be2[i] - m2[i] * inv2;
    }
}

// One wave per site; lane l owns channels l and l+64.
// Block = 1024 threads = 16 waves; each block covers 128 sites of one batch b.
__global__ __launch_bounds__(1024) void snn_main(
    const float* __restrict__ x,
    const float* __restrict__ w1, const float* __restrict__ b1,
    const float* __restrict__ b2, const float* __restrict__ ws,
    float* __restrict__ feat)
{
    __shared__ float smem[H_ * H_];   // w2t during loop; reduction buffer after

    const int tid  = threadIdx.x;
    const int lane = tid & 63;
    const int wave = tid >> 6;        // 0..15

    // stage w2t (64KB) into LDS, coalesced float4
    {
        const float4* src = (const float4*)(ws + WS_W2T);
        float4* dst = (float4*)smem;
        #pragma unroll
        for (int i = 0; i < 4; ++i) dst[tid + i * 1024] = src[tid + i * 1024];
    }

    const int p = lane;        // channel A
    const int q = lane + 64;   // channel B

    // per-channel constants (L1-cached broadcasts)
    float w10a = w1[p*3+0], w11a = w1[p*3+1], w12a = w1[p*3+2];
    float w10b = w1[q*3+0], w11b = w1[q*3+1], w12b = w1[q*3+2];
    float b1a = b1[p], b1b = b1[q];
    float i1a = ws[WS_INV1+p], i1b = ws[WS_INV1+q];
    float d1a = ws[WS_D1+p],  d1b = ws[WS_D1+q];
    float b2a = b2[p], b2b = b2[q];
    float i2a = ws[WS_INV2+p], i2b = ws[WS_INV2+q];
    float d2a = ws[WS_D2+p],  d2b = ws[WS_D2+q];

    const int b     = blockIdx.x >> 6;   // 64 blocks per batch
    const int chunk = blockIdx.x & 63;

    float facc_a = 0.f, facc_b = 0.f;

    __syncthreads();

    for (int it = 0; it < 8; ++it) {
        int site = chunk * 128 + it * 16 + wave;    // 0..8191 within batch b
        int t = site >> 4, v = site & 15;
        const float* xp = x + (((size_t)b * T_ + t) * C_) * V_ + v;
        float x0 = xp[0], x1 = xp[V_], x2 = xp[2 * V_];   // uniform -> scalar loads

        // fc1 + BN1, reference rounding order
        float h1a = ((x0 * w10a + x1 * w11a + x2 * w12a) + b1a) * i1a + d1a;
        float h1b = ((x0 * w10b + x1 * w11b + x2 * w12b) + b1b) * i1b + d1b;

        // LIF1 exact 4-step simulation -> first spike step k (0 = never)
        int ka = 0, kb = 0;
        {
            float va = 0.f, vb = 0.f;
            #pragma unroll
            for (int s = 1; s <= 4; ++s) {
                va = va + (h1a - va) * 0.5f;
                vb = vb + (h1b - vb) * 0.5f;
                bool sa  = (va - 0.5f) >= 0.f;
                bool sb2 = (vb - 0.5f) >= 0.f;
                if (sa)  { if (ka == 0) ka = s; va = 0.f; }
                if (sb2) { if (kb == 0) kb = s; vb = 0.f; }
            }
        }

        // class masks (wave-uniform SGPRs): A=k1, B=k2, C=k3, D=k4
        unsigned long long mA0 = __ballot(ka == 1), mA1 = __ballot(kb == 1);
        unsigned long long mB0 = __ballot(ka == 2), mB1 = __ballot(kb == 2);
        unsigned long long mC0 = __ballot(ka == 3), mC1 = __ballot(kb == 3);
        unsigned long long mD0 = __ballot(ka == 4), mD1 = __ballot(kb == 4);

        float SAa=0,SAb=0,SBa=0,SBb=0,SCa=0,SCb=0,SDa=0,SDb=0;

        #define ACC(mask, obase, Sa, Sb)                            \
            { unsigned long long m = (mask);                        \
              while (m) {                                           \
                  int o = (obase) + __builtin_ctzll(m);             \
                  m &= m - 1;                                       \
                  int idx = o * H_ + p;                             \
                  Sa += smem[idx];                                  \
                  Sb += smem[idx + 64];                             \
              } }

        ACC(mA0, 0, SAa, SAb) ACC(mA1, 64, SAa, SAb)
        ACC(mB0, 0, SBa, SBb) ACC(mB1, 64, SBa, SBb)
        ACC(mC0, 0, SCa, SCb) ACC(mC1, 64, SCa, SCb)
        ACC(mD0, 0, SDa, SDb) ACC(mD1, 64, SDa, SDb)
        #undef ACC

        // per-step raw dots: step1=SA, step2=SA+SB, step3=SA+SC, step4=SA+SB+SD
        float r1a = SAa, r2a = SAa + SBa, r3a = SAa + SCa, r4a = SAa + SBa + SDa;
        float r1b = SAb, r2b = SAb + SBb, r3b = SAb + SCb, r4b = SAb + SBb + SDb;

        float h2a[4] = { (r1a + b2a) * i2a + d2a, (r2a + b2a) * i2a + d2a,
                         (r3a + b2a) * i2a + d2a, (r4a + b2a) * i2a + d2a };
        float h2b[4] = { (r1b + b2b) * i2b + d2b, (r2b + b2b) * i2b + d2b,
                         (r3b + b2b) * i2b + d2b, (r4b + b2b) * i2b + d2b };

        // LIF2, exact reference rounding
        float va = 0.f, vb = 0.f;
        #pragma unroll
        for (int s = 0; s < 4; ++s) {
            va = va + (h2a[s] - va) * 0.5f;
            vb = vb + (h2b[s] - vb) * 0.5f;
            bool sa  = (va - 0.5f) >= 0.f;
            bool sb2 = (vb - 0.5f) >= 0.f;
            if (sa)  { facc_a += 1.f; va = 0.f; }
            if (sb2) { facc_b += 1.f; vb = 0.f; }
        }
    }

    // block reduction (reuse smem; all partial sums are exact small integers)
    __syncthreads();
    smem[wave * H_ + p] = facc_a;
    smem[wave * H_ + q] = facc_b;
    __syncthreads();
    if (wave == 0) {
        float sa = 0.f, sb = 0.f;
        #pragma unroll
        for (int w = 0; w < 16; ++w) { sa += smem[w * H_ + p]; sb += smem[w * H_ + q]; }
        atomicAdd(&feat[b * H_ + p], sa);
        atomicAdd(&feat[b * H_ + q], sb);
    }
}

__global__ void classifier_kernel(const float* __restrict__ feat,
                                  const float* __restrict__ wc,
                                  const float* __restrict__ bc,
                                  float* __restrict__ out) {
    int i = threadIdx.x;
    if (i >= B_ * NC_) return;
    int b = i / NC_, n = i % NC_;
    const float sc = 1.0f / 32768.0f;   // 1/(S*T*V), exact pow2
    float s = 0.f;
    for (int h = 0; h < H_; ++h) s += (feat[b * H_ + h] * sc) * wc[n * H_ + h];
    out[i] = s + bc[n];
}

extern "C" void kernel_launch(void* const* d_in, const int* in_sizes, int n_in,
                              void* d_out, int out_size, void* d_ws, size_t ws_size,
                              hipStream_t stream) {
    const float* x   = (const float*)d_in[0];
    const float* w1  = (const float*)d_in[1];
    const float* b1  = (const float*)d_in[2];
    const float* g1  = (const float*)d_in[3];
    const float* be1 = (const float*)d_in[4];
    const float* m1  = (const float*)d_in[5];
    const float* rv1 = (const float*)d_in[6];
    const float* w2  = (const float*)d_in[7];
    const float* b2  = (const float*)d_in[8];
    const float* g2  = (const float*)d_in[9];
    const float* be2 = (const float*)d_in[10];
    const float* m2  = (const float*)d_in[11];
    const float* rv2 = (const float*)d_in[12];
    const float* wc  = (const float*)d_in[13];
    const float* bc  = (const float*)d_in[14];
    float* ws  = (float*)d_ws;
    float* out = (float*)d_out;

    prep_kernel<<<64, 256, 0, stream>>>(w2, g1, be1, m1, rv1, g2, be2, m2, rv2, ws);
    hipMemsetAsync(ws + WS_FEAT, 0, B_ * H_ * sizeof(float), stream);
    snn_main<<<1024, 1024, 0, stream>>>(x, w1, b1, b2, ws, ws + WS_FEAT);
    classifier_kernel<<<1, 256, 0, stream>>>(ws + WS_FEAT, wc, bc, out);
}

// Round 2
// 147.945 us; speedup vs baseline: 1.0722x; 1.0722x over previous
//
#include <hip/hip_runtime.h>
#include <stdint.h>
#include <math.h>

#define B_ 16
#define T_ 512
#define C_ 3
#define V_ 16
#define H_ 128
#define NC_ 12

// workspace layout (float offsets)
#define WS_W2P   0        // 16384: w2 pair-interleaved: [o][l] = (w2[l][o], w2[l+64][o])
#define WS_INV1  16384    // 128
#define WS_D1    16512    // 128
#define WS_INV2  16640    // 128
#define WS_D2    16768    // 128
#define WS_FEAT  16896    // 2048: per-(b,h) spike totals
// total 18944 floats = 75776 bytes

__global__ void prep_kernel(const float* __restrict__ w2,
                            const float* __restrict__ g1, const float* __restrict__ be1,
                            const float* __restrict__ m1, const float* __restrict__ rv1,
                            const float* __restrict__ g2, const float* __restrict__ be2,
                            const float* __restrict__ m2, const float* __restrict__ rv2,
                            float* __restrict__ ws) {
    int i = blockIdx.x * blockDim.x + threadIdx.x;
    if (i < H_ * H_) {
        // pair-interleaved transpose: ws[o*128 + 2*l + h] = w2[(l + 64*h)*128 + o]
        int o = i >> 7, j = i & (H_ - 1);
        int l = j >> 1, hh = j & 1;
        ws[WS_W2P + i] = w2[(l + 64 * hh) * H_ + o];
    } else if (i >= H_ * H_ && i < H_ * H_ + B_ * H_) {
        ws[WS_FEAT + (i - H_ * H_)] = 0.0f;   // zero feat accumulators
    }
    if (i < H_) {
        float r1 = (float)(1.0 / sqrt((double)(rv1[i] + 1e-5f)));
        float inv1 = g1[i] * r1;
        ws[WS_INV1 + i] = inv1;
        ws[WS_D1 + i] = be1[i] - m1[i] * inv1;
        float r2 = (float)(1.0 / sqrt((double)(rv2[i] + 1e-5f)));
        float inv2 = g2[i] * r2;
        ws[WS_INV2 + i] = inv2;
        ws[WS_D2 + i] = be2[i] - m2[i] * inv2;
    }
}

// One wave per site; lane l owns channels l and l+64 (adjacent in paired LDS layout).
// Block = 1024 threads = 16 waves; each block covers 128 sites of one batch b.
__global__ __launch_bounds__(1024) void snn_main(
    const float* __restrict__ x,
    const float* __restrict__ w1, const float* __restrict__ b1,
    const float* __restrict__ b2, const float* __restrict__ ws,
    float* __restrict__ feat)
{
    __shared__ float smem[H_ * H_];   // paired w2 during loop; reduction buffer after

    const int tid  = threadIdx.x;
    const int lane = tid & 63;
    const int wave = tid >> 6;        // 0..15

    // stage paired w2 (64KB) into LDS, coalesced float4
    {
        const float4* src = (const float4*)(ws + WS_W2P);
        float4* dst = (float4*)smem;
        #pragma unroll
        for (int i = 0; i < 4; ++i) dst[tid + i * 1024] = src[tid + i * 1024];
    }

    const int p = lane;        // channel A
    const int q = lane + 64;   // channel B

    // per-channel constants (L1-cached broadcasts)
    float w10a = w1[p*3+0], w11a = w1[p*3+1], w12a = w1[p*3+2];
    float w10b = w1[q*3+0], w11b = w1[q*3+1], w12b = w1[q*3+2];
    float b1a = b1[p], b1b = b1[q];
    float i1a = ws[WS_INV1+p], i1b = ws[WS_INV1+q];
    float d1a = ws[WS_D1+p],  d1b = ws[WS_D1+q];
    float b2a = b2[p], b2b = b2[q];
    float i2a = ws[WS_INV2+p], i2b = ws[WS_INV2+q];
    float d2a = ws[WS_D2+p],  d2b = ws[WS_D2+q];

    const int b     = blockIdx.x >> 6;   // 64 blocks per batch
    const int chunk = blockIdx.x & 63;

    // per-lane base pointer into paired rows: row o lives at float2 index o*64 + lane
    const float2* wrow = ((const float2*)smem) + lane;

    float facc_a = 0.f, facc_b = 0.f;

    __syncthreads();

    for (int it = 0; it < 8; ++it) {
        int site = chunk * 128 + it * 16 + wave;    // 0..8191 within batch b
        int t = site >> 4, v = site & 15;
        const float* xp = x + (((size_t)b * T_ + t) * C_) * V_ + v;
        float x0 = xp[0], x1 = xp[V_], x2 = xp[2 * V_];   // uniform -> scalar loads

        // fc1 + BN1, reference rounding order
        float h1a = ((x0 * w10a + x1 * w11a + x2 * w12a) + b1a) * i1a + d1a;
        float h1b = ((x0 * w10b + x1 * w11b + x2 * w12b) + b1b) * i1b + d1b;

        // LIF1 exact 4-step simulation -> first spike step k (0 = never)
        int ka = 0, kb = 0;
        {
            float va = 0.f, vb = 0.f;
            #pragma unroll
            for (int s = 1; s <= 4; ++s) {
                va = va + (h1a - va) * 0.5f;
                vb = vb + (h1b - vb) * 0.5f;
                bool sa  = (va - 0.5f) >= 0.f;
                bool sb2 = (vb - 0.5f) >= 0.f;
                if (sa)  { if (ka == 0) ka = s; va = 0.f; }
                if (sb2) { if (kb == 0) kb = s; vb = 0.f; }
            }
        }

        // class masks (wave-uniform SGPRs): A=k1, B=k2, C=k3, D=k4
        unsigned long long mA0 = __ballot(ka == 1), mA1 = __ballot(kb == 1);
        unsigned long long mB0 = __ballot(ka == 2), mB1 = __ballot(kb == 2);
        unsigned long long mC0 = __ballot(ka == 3), mC1 = __ballot(kb == 3);
        unsigned long long mD0 = __ballot(ka == 4), mD1 = __ballot(kb == 4);

        float SAa=0,SAb=0,SBa=0,SBb=0,SCa=0,SCb=0,SDa=0,SDb=0;

        #define ACC(mask, obase, Sa, Sb)                            \
            { unsigned long long m = (mask);                        \
              while (m) {                                           \
                  int o = (obase) + __builtin_ctzll(m);             \
                  m &= m - 1;                                       \
                  float2 wv = wrow[o << 6];                         \
                  Sa += wv.x;                                       \
                  Sb += wv.y;                                       \
              } }

        ACC(mA0, 0, SAa, SAb) ACC(mA1, 64, SAa, SAb)
        ACC(mB0, 0, SBa, SBb) ACC(mB1, 64, SBa, SBb)
        ACC(mC0, 0, SCa, SCb) ACC(mC1, 64, SCa, SCb)
        ACC(mD0, 0, SDa, SDb) ACC(mD1, 64, SDa, SDb)
        #undef ACC

        // per-step raw dots: step1=SA, step2=SA+SB, step3=SA+SC, step4=SA+SB+SD
        float r1a = SAa, r2a = SAa + SBa, r3a = SAa + SCa, r4a = SAa + SBa + SDa;
        float r1b = SAb, r2b = SAb + SBb, r3b = SAb + SCb, r4b = SAb + SBb + SDb;

        float h2a[4] = { (r1a + b2a) * i2a + d2a, (r2a + b2a) * i2a + d2a,
                         (r3a + b2a) * i2a + d2a, (r4a + b2a) * i2a + d2a };
        float h2b[4] = { (r1b + b2b) * i2b + d2b, (r2b + b2b) * i2b + d2b,
                         (r3b + b2b) * i2b + d2b, (r4b + b2b) * i2b + d2b };

        // LIF2, exact reference rounding
        float va = 0.f, vb = 0.f;
        #pragma unroll
        for (int s = 0; s < 4; ++s) {
            va = va + (h2a[s] - va) * 0.5f;
            vb = vb + (h2b[s] - vb) * 0.5f;
            bool sa  = (va - 0.5f) >= 0.f;
            bool sb2 = (vb - 0.5f) >= 0.f;
            if (sa)  { facc_a += 1.f; va = 0.f; }
            if (sb2) { facc_b += 1.f; vb = 0.f; }
        }
    }

    // block reduction (reuse smem; all partial sums are exact small integers)
    __syncthreads();
    smem[wave * H_ + p] = facc_a;
    smem[wave * H_ + q] = facc_b;
    __syncthreads();
    if (wave == 0) {
        float sa = 0.f, sb = 0.f;
        #pragma unroll
        for (int w = 0; w < 16; ++w) { sa += smem[w * H_ + p]; sb += smem[w * H_ + q]; }
        atomicAdd(&feat[b * H_ + p], sa);
        atomicAdd(&feat[b * H_ + q], sb);
    }
}

// one wave per (b, n) output element
__global__ __launch_bounds__(64) void classifier_kernel(
    const float* __restrict__ feat,
    const float* __restrict__ wc,
    const float* __restrict__ bc,
    float* __restrict__ out) {
    int bn = blockIdx.x;
    int b = bn / NC_, n = bn % NC_;
    int l = threadIdx.x;
    const float sc = 1.0f / 32768.0f;   // 1/(S*T*V), exact pow2
    float2 f = *(const float2*)(feat + b * H_ + 2 * l);
    float2 w = *(const float2*)(wc + n * H_ + 2 * l);
    float s = (f.x * sc) * w.x + (f.y * sc) * w.y;
    #pragma unroll
    for (int off = 32; off > 0; off >>= 1) s += __shfl_down(s, off);
    if (l == 0) out[bn] = s + bc[n];
}

extern "C" void kernel_launch(void* const* d_in, const int* in_sizes, int n_in,
                              void* d_out, int out_size, void* d_ws, size_t ws_size,
                              hipStream_t stream) {
    const float* x   = (const float*)d_in[0];
    const float* w1  = (const float*)d_in[1];
    const float* b1  = (const float*)d_in[2];
    const float* g1  = (const float*)d_in[3];
    const float* be1 = (const float*)d_in[4];
    const float* m1  = (const float*)d_in[5];
    const float* rv1 = (const float*)d_in[6];
    const float* w2  = (const float*)d_in[7];
    const float* b2  = (const float*)d_in[8];
    const float* g2  = (const float*)d_in[9];
    const float* be2 = (const float*)d_in[10];
    const float* m2  = (const float*)d_in[11];
    const float* rv2 = (const float*)d_in[12];
    const float* wc  = (const float*)d_in[13];
    const float* bc  = (const float*)d_in[14];
    float* ws  = (float*)d_ws;
    float* out = (float*)d_out;

    // 80 blocks x 256 covers transpose (16384) + feat zero (2048)
    prep_kernel<<<80, 256, 0, stream>>>(w2, g1, be1, m1, rv1, g2, be2, m2, rv2, ws);
    snn_main<<<1024, 1024, 0, stream>>>(x, w1, b1, b2, ws, ws + WS_FEAT);
    classifier_kernel<<<B_ * NC_, 64, 0, stream>>>(ws + WS_FEAT, wc, bc, out);
}